// Round 9
// baseline (163.186 us; speedup 1.0000x reference)
//
#include <hip/hip_runtime.h>
#include <hip/hip_bf16.h>
#include <math.h>

#define BB 4
#define CC 256
#define DKK 32
#define NN 4096
// 1/sqrt(32) * log2(e) — folded into q at QKV epilogue; attention uses raw
// v_exp_f32 (2^x): removes 32 v_mul/iter/wave from the VALU pipe.
#define QSCALE2 0.25503489022324213f

typedef __attribute__((ext_vector_type(8))) __bf16 bf16x8;
typedef __attribute__((ext_vector_type(4))) __bf16 bf16x4;
typedef __attribute__((ext_vector_type(4))) float f32x4;
typedef __attribute__((ext_vector_type(16))) float f32x16;

// ---------------------------------------------------------------------------
// Kernel 1 (fused): QKV projection reading x/W fp32 directly.
// Block: 32 n x 320 o; wave w -> o 80w..80w+79. Grid 128 x B.
// Outputs: q,k (B,N,32) bf16 (q pre-scaled by QSCALE2); V tiled for 32x32
// MFMA A-frags: [b][chunk n/32][ct c/32][kb (n%32)/16][c%32][n%16].
// ---------------------------------------------------------------------------
#define XROW 264   // LDS row stride (bf16 elems) for x-tile: 528B rows

__global__ __launch_bounds__(256) void qkv2_kernel(
    const float* __restrict__ x,
    const float* __restrict__ Wq, const float* __restrict__ Wk,
    const float* __restrict__ Wv,
    const float* __restrict__ bq, const float* __restrict__ bk,
    const float* __restrict__ bv,
    __bf16* __restrict__ qws, __bf16* __restrict__ kws, __bf16* __restrict__ vws)
{
    // overlay: xs (32 x XROW bf16, 16896B) for the GEMM; scr (64x33 f32,
    // 8448B) for the q/k epilogue transpose (used strictly after xs).
    __shared__ __align__(16) unsigned char smemB[32 * XROW * 2];
    __bf16* xs = (__bf16*)smemB;
    float (*scr)[33] = (float (*)[33])smemB;

    const int tid = threadIdx.x;
    const int w   = tid >> 6;
    const int l   = tid & 63;
    const int l15 = l & 15;
    const int lq  = l >> 4;
    const int n0  = blockIdx.x * 32;
    const int b   = blockIdx.y;

    // ---- stage x tile: read fp32 (coalesced 128B/row-segment), write
    //      transposed bf16 into LDS: xs[n][c] ----
    {
        const int cl = tid >> 3;          // 0..31: c within round
        const int nf = (tid & 7) * 4;     // 0..28
#pragma unroll
        for (int p = 0; p < 8; p++) {
            int c = p * 32 + cl;
            float4 v = *(const float4*)&x[((size_t)(b * CC + c)) * NN + n0 + nf];
            xs[(nf + 0) * XROW + c] = (__bf16)v.x;
            xs[(nf + 1) * XROW + c] = (__bf16)v.y;
            xs[(nf + 2) * XROW + c] = (__bf16)v.z;
            xs[(nf + 3) * XROW + c] = (__bf16)v.w;
        }
    }

    // per-(w,ot) W row pointers: o = 80w+16ot -> {Wq,Wk,Wv} row base + l15
    const float* wrow[5];
#pragma unroll
    for (int ot = 0; ot < 5; ot++) {
        int ob = 80 * w + ot * 16;
        const float* mat; int r0;
        if (ob < 32)      { mat = Wq; r0 = ob; }
        else if (ob < 64) { mat = Wk; r0 = ob - 32; }
        else              { mat = Wv; r0 = ob - 64; }
        wrow[ot] = mat + (size_t)(r0 + l15) * CC + lq * 8;
    }

    __syncthreads();

    const f32x4 zf = {0.f, 0.f, 0.f, 0.f};
    f32x4 acc[5][2];
#pragma unroll
    for (int i = 0; i < 5; i++)
#pragma unroll
        for (int j = 0; j < 2; j++) acc[i][j] = zf;

    const __bf16* xls = &xs[l15 * XROW + lq * 8];

    bf16x8 bcur[2], acur[5], bnxt[2], anxt[5];
#pragma unroll
    for (int nt = 0; nt < 2; nt++) bcur[nt] = *(const bf16x8*)(xls + nt * 16 * XROW);
#pragma unroll
    for (int ot = 0; ot < 5; ot++) {
        f32x4 a0 = *(const f32x4*)(wrow[ot]);
        f32x4 a1 = *(const f32x4*)(wrow[ot] + 4);
        bf16x8 af;
#pragma unroll
        for (int j = 0; j < 4; j++) { af[j] = (__bf16)a0[j]; af[4 + j] = (__bf16)a1[j]; }
        acur[ot] = af;
    }

#pragma unroll
    for (int ks = 0; ks < 8; ks++) {
        if (ks < 7) {
#pragma unroll
            for (int nt = 0; nt < 2; nt++)
                bnxt[nt] = *(const bf16x8*)(xls + nt * 16 * XROW + (ks + 1) * 32);
#pragma unroll
            for (int ot = 0; ot < 5; ot++) {
                f32x4 a0 = *(const f32x4*)(wrow[ot] + (ks + 1) * 32);
                f32x4 a1 = *(const f32x4*)(wrow[ot] + (ks + 1) * 32 + 4);
                bf16x8 af;
#pragma unroll
                for (int j = 0; j < 4; j++) { af[j] = (__bf16)a0[j]; af[4 + j] = (__bf16)a1[j]; }
                anxt[ot] = af;
            }
        }
#pragma unroll
        for (int ot = 0; ot < 5; ot++)
#pragma unroll
            for (int nt = 0; nt < 2; nt++)
                acc[ot][nt] = __builtin_amdgcn_mfma_f32_16x16x32_bf16(acur[ot], bcur[nt], acc[ot][nt], 0, 0, 0);
        if (ks < 7) {
#pragma unroll
            for (int nt = 0; nt < 2; nt++) bcur[nt] = bnxt[nt];
#pragma unroll
            for (int ot = 0; ot < 5; ot++) acur[ot] = anxt[ot];
        }
    }

    __syncthreads();   // all xs reads complete before scr overlays the LDS

    // epilogue: D row o = 80w + ot*16 + lq*4 + r, col n = nt*16 + l15
    // V store layout: vchunk[ct*1024 + kb*512 + (c&31)*16 + (n&15)]
    __bf16* vchunk = vws + (size_t)b * CC * NN + (size_t)(n0 >> 5) * 8192;
#pragma unroll
    for (int ot = 0; ot < 5; ot++) {
        int ob = 80 * w + ot * 16;
#pragma unroll
        for (int nt = 0; nt < 2; nt++) {
#pragma unroll
            for (int r = 0; r < 4; r++) {
                int o = ob + lq * 4 + r;
                int n = nt * 16 + l15;
                float val = acc[ot][nt][r];
                if (ob >= 64) {
                    int c  = o - 64;
                    int ct = c >> 5, c5 = c & 31;
                    vchunk[ct * 1024 + nt * 512 + c5 * 16 + l15] =
                        (__bf16)(val + bv[c]);
                } else if (ob < 32) {
                    scr[o][n] = (val + bq[o]) * QSCALE2;
                } else {
                    scr[o][n] = val + bk[o - 32];
                }
            }
        }
    }
    __syncthreads();
    {
        int n  = tid >> 3;            // 0..31
        int d0 = (tid & 7) * 4;       // 0..28
        bf16x4 qv, kv;
#pragma unroll
        for (int j = 0; j < 4; j++) {
            qv[j] = (__bf16)scr[d0 + j][n];
            kv[j] = (__bf16)scr[32 + d0 + j][n];
        }
        size_t base = ((size_t)b * NN + n0 + n) * DKK + d0;
        *(bf16x4*)&qws[base] = qv;
        *(bf16x4*)&kws[base] = kv;
    }
}

// ---------------------------------------------------------------------------
// Kernel 2: flash attention — c-SPLIT WAVES + barrier-pipelined SHARED P.
// Round-9 restructure (attacks "2 fat waves/SIMD can't hide per-wave serial
// chains", the wall R5/R7/R8 all hit at ~55us):
//  - block = 32 m x 128 c (ch half), grid 1024; 4 waves each own a 32-c
//    slice -> acc = ONE f32x16 (16 AGPR, was 128). __launch_bounds__(256,4)
//    -> 4 blocks/CU = 4 waves/SIMD (2x TLP).
//  - per iter (128-n chunk): wave w computes P-slice for n-subchunk w
//    (2 KQ MFMA + 16 exp + 4 permlane — R7-verified math), writes b128
//    B-frags to shared LDS pbuf[2][chunk j][kk][hi][m31]; ONE barrier/iter;
//    each wave PVs its c-slice over all 4 chunks (8 MFMA). PV(ic) is
//    decoupled from KQ(ic+1) across waves via the double buffer.
//  - epilogue collapses: each wave owns complete O columns -> no cross-wave
//    O reduce, no Ored LDS; normalize = broadcast Linv[m31] per lane.
// Audited peak ~95 VGPR + 16 AGPR; kill criterion: spill (WRITE_SIZE>17MB).
// ---------------------------------------------------------------------------
__global__ __launch_bounds__(256, 4) void attn_kernel(
    const __bf16* __restrict__ qb, const __bf16* __restrict__ kb,
    const __bf16* __restrict__ vt, const float* __restrict__ x,
    float* __restrict__ out)
{
    // [0, 16384)       pbuf: 2 bufs x 4 chunks x [kk][hi][m31] x 16B
    // [16384, 17408)   Ls[8][32]  (w*2+hi partials per m)
    // [17408, 17536)   Linv[32]
    __shared__ __align__(16) unsigned char smem[17536];
    unsigned char* pbuf = smem;
    float* Ls   = (float*)(smem + 16384);
    float* Linv = (float*)(smem + 17408);

    const int tid = threadIdx.x;
    const int w   = tid >> 6;
    const int l   = tid & 63;
    const int m31 = l & 31;           // MFMA col lane (m)
    const int hi  = l >> 5;           // k-half lane

    // XCD swizzle: batch pinned to an XCD pair -> K/V/Q stay L2-resident
    const int beta = blockIdx.x;
    const int b    = (beta >> 1) & 3;
    const int ch   = (beta >> 3) & 1;                        // c-half
    const int mt32 = ((beta >> 4) << 1) | (beta & 1);        // 0..127
    const int m0   = mt32 * 32;

    const __bf16* qbb = qb + (size_t)b * NN * DKK;
    const __bf16* kbb = kb + (size_t)b * NN * DKK;
    const __bf16* vtb = vt + (size_t)b * CC * NN;

    // Q B-frags: qa[kk]: Q[m0+m31][kk*16 + hi*8 + j]
    bf16x8 qa[2];
#pragma unroll
    for (int kk = 0; kk < 2; kk++)
        qa[kk] = *(const bf16x8*)(qbb + (size_t)(m0 + m31) * DKK + kk * 16 + hi * 8);

    // K A-frag strip: wave w's n-subchunk rows (ic*128 + w*32 + m31)
    const __bf16* kstrip = kbb + (size_t)(w * 32 + m31) * DKK + hi * 8;
    // V A-frag strip: wave w's c-slice: ct = ch*4+w; + chunk*8192 + kb*512
    const __bf16* vstrip = vtb + (size_t)(ch * 4 + w) * 1024 + m31 * 16 + hi * 8;

    const f32x16 zf16 = {0.f,0.f,0.f,0.f,0.f,0.f,0.f,0.f,
                         0.f,0.f,0.f,0.f,0.f,0.f,0.f,0.f};
    f32x16 acc = zf16;                // 16 AGPR: O[32c-slice][32m]
    float lacc = 0.f;

    // KQ + exp + in-register P assembly (permlane32_swap, R7-verified),
    // then publish the B-frags to shared LDS.
    // e reg g*4+t -> n = g*8 + 4*hi + t. After swap: pf[kk] elem j (lane
    // m31,hi) = P[kk*16+hi*8+j][m31] — written at [buf][w][kk][hi][m31].
    union PU { unsigned u[4]; bf16x8 v; };
    auto kq_store = [&](int buf, bf16x8 k0, bf16x8 k1) {
        f32x16 e = __builtin_amdgcn_mfma_f32_32x32x16_bf16(k0, qa[0], zf16, 0, 0, 0);
        e = __builtin_amdgcn_mfma_f32_32x32x16_bf16(k1, qa[1], e, 0, 0, 0);
        float s = 0.f;
        unsigned g[4][2];
#pragma unroll
        for (int gi = 0; gi < 4; gi++) {
            bf16x4 pb;
#pragma unroll
            for (int t = 0; t < 4; t++) {
                float v = __builtin_amdgcn_exp2f(e[4 * gi + t]);
                s += v; pb[t] = (__bf16)v;
            }
            PU tu; *(bf16x4*)tu.u = pb;
            g[gi][0] = tu.u[0]; g[gi][1] = tu.u[1];
        }
        lacc += s;
#pragma unroll
        for (int kk = 0; kk < 2; kk++) {
            PU r;
#pragma unroll
            for (int wi = 0; wi < 2; wi++) {
                auto sw = __builtin_amdgcn_permlane32_swap(
                    (int)g[kk * 2][wi], (int)g[kk * 2 + 1][wi], false, false);
                r.u[wi]     = (unsigned)sw[0];
                r.u[2 + wi] = (unsigned)sw[1];
            }
            *(bf16x8*)(pbuf + buf * 8192 + w * 2048 + kk * 1024 + hi * 512 + m31 * 16) = r.v;
        }
    };

    // ---- prologue: P(0) -> buf 0; prefetch K(1) ----
    {
        bf16x8 k0 = *(const bf16x8*)kstrip;
        bf16x8 k1 = *(const bf16x8*)(kstrip + 16);
        kq_store(0, k0, k1);
    }
    bf16x8 kA0 = *(const bf16x8*)(kstrip + (size_t)128 * DKK);
    bf16x8 kA1 = *(const bf16x8*)(kstrip + (size_t)128 * DKK + 16);
    __syncthreads();

    // ---- main loop: ONE barrier per 128-n chunk ----
#pragma unroll 1
    for (int ic = 0; ic < 32; ic++) {
        const int cur = ic & 1;
        const __bf16* vch = vstrip + (size_t)ic * 32768;

        // V frags for PV(ic): issued first, covered by the KQ/exp phase
        bf16x8 vf[8];
#pragma unroll
        for (int j = 0; j < 4; j++)
#pragma unroll
            for (int kk = 0; kk < 2; kk++)
                vf[j * 2 + kk] = *(const bf16x8*)(vch + j * 8192 + kk * 512);

        // KQ(ic+1) -> buf[cur^1]; K(ic+2) reload in place
        if (ic < 31) {
            kq_store(cur ^ 1, kA0, kA1);
            kA0 = *(const bf16x8*)(kstrip + (size_t)(ic + 2) * 128 * DKK);
            kA1 = *(const bf16x8*)(kstrip + (size_t)(ic + 2) * 128 * DKK + 16);
        }

        // PV(ic): 4 chunks x 2 k-halves into the single acc
        __builtin_amdgcn_s_setprio(1);
#pragma unroll
        for (int j = 0; j < 4; j++)
#pragma unroll
            for (int kk = 0; kk < 2; kk++) {
                bf16x8 pf = *(const bf16x8*)(pbuf + cur * 8192 + j * 2048 + kk * 1024 + hi * 512 + m31 * 16);
                acc = __builtin_amdgcn_mfma_f32_32x32x16_bf16(vf[j * 2 + kk], pf, acc, 0, 0, 0);
            }
        __builtin_amdgcn_s_setprio(0);
        __syncthreads();
    }

    // ---- l: publish 8 partials per m (4 waves x 2 hi-halves) ----
    Ls[(w * 2 + hi) * 32 + m31] = lacc;
    __syncthreads();
    if (tid < 32) {
        float s = 0.f;
#pragma unroll
        for (int r = 0; r < 8; r++) s += Ls[r * 32 + tid];
        Linv[tid] = 1.0f / s;
    }
    __syncthreads();
    const float li = Linv[m31];

    // ---- epilogue: direct store (wave owns complete O columns) ----
    // acc[reg]: c = ch*128 + w*32 + crow, crow=(reg&3)+8*(reg>>2)+4*hi;
    // m = m0 + m31.
#pragma unroll
    for (int reg = 0; reg < 16; reg++) {
        int crow = (reg & 3) + 8 * (reg >> 2) + 4 * hi;
        int c = ch * 128 + w * 32 + crow;
        size_t gi = ((size_t)(b * CC + c)) * NN + m0 + m31;
        out[gi] = acc[reg] * li + x[gi];
    }
}

extern "C" void kernel_launch(void* const* d_in, const int* in_sizes, int n_in,
                              void* d_out, int out_size, void* d_ws, size_t ws_size,
                              hipStream_t stream) {
    const float* x  = (const float*)d_in[0];
    const float* Wq = (const float*)d_in[1];
    const float* bq = (const float*)d_in[2];
    const float* Wk = (const float*)d_in[3];
    const float* bk = (const float*)d_in[4];
    const float* Wv = (const float*)d_in[5];
    const float* bv = (const float*)d_in[6];
    float* out = (float*)d_out;

    __bf16* qws = (__bf16*)d_ws;                       // B*N*32
    __bf16* kws = qws + (size_t)BB * NN * DKK;         // B*N*32
    __bf16* vws = kws + (size_t)BB * NN * DKK;         // B*C*N (tiled)

    qkv2_kernel<<<dim3(128, BB), 256, 0, stream>>>(x, Wq, Wk, Wv, bq, bk, bv,
                                                   qws, kws, vws);
    attn_kernel<<<dim3(1024), 256, 0, stream>>>(qws, kws, vws, x, out);
}

// Round 10
// 148.329 us; speedup vs baseline: 1.1002x; 1.1002x over previous
//
#include <hip/hip_runtime.h>
#include <hip/hip_bf16.h>
#include <math.h>

#define BB 4
#define CC 256
#define DKK 32
#define NN 4096
// 1/sqrt(32) * log2(e) — folded into q at QKV epilogue; attention uses raw
// v_exp_f32 (2^x).
#define QSCALE2 0.25503489022324213f

typedef __attribute__((ext_vector_type(8))) __bf16 bf16x8;
typedef __attribute__((ext_vector_type(4))) __bf16 bf16x4;
typedef __attribute__((ext_vector_type(4))) float f32x4;
typedef __attribute__((ext_vector_type(16))) float f32x16;

// ---------------------------------------------------------------------------
// Kernel 0: fused (a) x transpose (B,C,N) fp32 -> xT (B,N,C) bf16,
//           (b) W fp32 -> bf16 Wb[320][256] (done by 80 of the blocks).
// RESTORED (R2 had fused this into qkv; that made every qkv block re-read
// fp32 W from L2 with 16-way-split requests — residue rose ~4-5us. One-time
// bf16 conversion + coalesced bf16 reads is the cheaper global schedule.)
// ---------------------------------------------------------------------------
__global__ __launch_bounds__(256) void prep_kernel(
    const float* __restrict__ x, __bf16* __restrict__ xT,
    const float* __restrict__ Wq, const float* __restrict__ Wk,
    const float* __restrict__ Wv, __bf16* __restrict__ Wb)
{
    __shared__ float xs[64][68];
    const int tid = threadIdx.x;
    const int n0 = blockIdx.x * 64;
    const int c0 = blockIdx.y * 64;
    const int b  = blockIdx.z;

    if (b == 0) {
        int unit = blockIdx.y * 64 + blockIdx.x;
        if (unit < 80) {
            int i = (unit * 256 + tid) * 4;
            int row = i >> 8, col = i & 255;
            const float* src;
            if (row < 32)      src = &Wq[row * 256 + col];
            else if (row < 64) src = &Wk[(row - 32) * 256 + col];
            else               src = &Wv[(row - 64) * 256 + col];
            float4 v = *(const float4*)src;
            Wb[i]     = (__bf16)v.x;
            Wb[i + 1] = (__bf16)v.y;
            Wb[i + 2] = (__bf16)v.z;
            Wb[i + 3] = (__bf16)v.w;
        }
    }

#pragma unroll
    for (int p = 0; p < 4; p++) {
        int cc = p * 16 + (tid >> 4);
        int nf = (tid & 15) * 4;
        float4 v = *(const float4*)&x[((size_t)(b * CC + c0 + cc)) * NN + n0 + nf];
        xs[cc][nf] = v.x; xs[cc][nf + 1] = v.y; xs[cc][nf + 2] = v.z; xs[cc][nf + 3] = v.w;
    }
    __syncthreads();
    int n = tid >> 2, cs = (tid & 3) * 16;
    bf16x8 lo, hi;
#pragma unroll
    for (int j = 0; j < 8; j++) {
        lo[j] = (__bf16)xs[cs + j][n];
        hi[j] = (__bf16)xs[cs + 8 + j][n];
    }
    size_t base = ((size_t)(b * NN + n0 + n)) * CC + c0 + cs;
    *(bf16x8*)&xT[base]     = lo;
    *(bf16x8*)&xT[base + 8] = hi;
}

// ---------------------------------------------------------------------------
// Kernel 1: QKV projection — MFMA GEMM over bf16 xT/Wb (coalesced 16B
// loads), register depth-1 prefetch. Block: 32 n x 320 o; wave w -> o
// 80w..80w+79. Grid 128 x B. Outputs: q,k (B,N,32) bf16 (q pre-scaled by
// QSCALE2); V tiled for 32x32 MFMA A-frags:
// [b][chunk n/32][ct c/32][kb (n%32)/16][c%32][n%16].
// ---------------------------------------------------------------------------
__global__ __launch_bounds__(256) void qkv_kernel(
    const __bf16* __restrict__ xT, const __bf16* __restrict__ Wb,
    const float* __restrict__ bq, const float* __restrict__ bk,
    const float* __restrict__ bv,
    __bf16* __restrict__ qws, __bf16* __restrict__ kws, __bf16* __restrict__ vws)
{
    __shared__ float scr[64][33];

    const int tid = threadIdx.x;
    const int w   = tid >> 6;
    const int l   = tid & 63;
    const int l15 = l & 15;
    const int lq  = l >> 4;
    const int n0  = blockIdx.x * 32;
    const int b   = blockIdx.y;

    const __bf16* xbase = xT + ((size_t)b * NN + n0 + l15) * CC + lq * 8;
    const __bf16* wbase = Wb + (size_t)(80 * w + l15) * CC + lq * 8;

    const f32x4 zf = {0.f, 0.f, 0.f, 0.f};
    f32x4 acc[5][2];
#pragma unroll
    for (int i = 0; i < 5; i++)
#pragma unroll
        for (int j = 0; j < 2; j++) acc[i][j] = zf;

    bf16x8 bcur[2], acur[5], bnxt[2], anxt[5];
#pragma unroll
    for (int nt = 0; nt < 2; nt++) bcur[nt] = *(const bf16x8*)(xbase + nt * 16 * CC);
#pragma unroll
    for (int ot = 0; ot < 5; ot++) acur[ot] = *(const bf16x8*)(wbase + ot * 16 * CC);

#pragma unroll
    for (int ks = 0; ks < 8; ks++) {
        if (ks < 7) {
#pragma unroll
            for (int nt = 0; nt < 2; nt++)
                bnxt[nt] = *(const bf16x8*)(xbase + nt * 16 * CC + (ks + 1) * 32);
#pragma unroll
            for (int ot = 0; ot < 5; ot++)
                anxt[ot] = *(const bf16x8*)(wbase + ot * 16 * CC + (ks + 1) * 32);
        }
#pragma unroll
        for (int ot = 0; ot < 5; ot++)
#pragma unroll
            for (int nt = 0; nt < 2; nt++)
                acc[ot][nt] = __builtin_amdgcn_mfma_f32_16x16x32_bf16(acur[ot], bcur[nt], acc[ot][nt], 0, 0, 0);
        if (ks < 7) {
#pragma unroll
            for (int nt = 0; nt < 2; nt++) bcur[nt] = bnxt[nt];
#pragma unroll
            for (int ot = 0; ot < 5; ot++) acur[ot] = anxt[ot];
        }
    }

    // epilogue: D row o = 80w + ot*16 + lq*4 + r, col n = nt*16 + l15
    // V store layout: vchunk[ct*1024 + kb*512 + (c&31)*16 + (n&15)]
    __bf16* vchunk = vws + (size_t)b * CC * NN + (size_t)(n0 >> 5) * 8192;
#pragma unroll
    for (int ot = 0; ot < 5; ot++) {
        int ob = 80 * w + ot * 16;
#pragma unroll
        for (int nt = 0; nt < 2; nt++) {
#pragma unroll
            for (int r = 0; r < 4; r++) {
                int o = ob + lq * 4 + r;
                int n = nt * 16 + l15;
                float val = acc[ot][nt][r];
                if (ob >= 64) {
                    int c  = o - 64;
                    int ct = c >> 5, c5 = c & 31;
                    vchunk[ct * 1024 + nt * 512 + c5 * 16 + l15] =
                        (__bf16)(val + bv[c]);
                } else if (ob < 32) {
                    scr[o][n] = (val + bq[o]) * QSCALE2;
                } else {
                    scr[o][n] = val + bk[o - 32];
                }
            }
        }
    }
    __syncthreads();
    {
        int n  = tid >> 3;            // 0..31
        int d0 = (tid & 7) * 4;       // 0..28
        bf16x4 qv, kv;
#pragma unroll
        for (int j = 0; j < 4; j++) {
            qv[j] = (__bf16)scr[d0 + j][n];
            kv[j] = (__bf16)scr[32 + d0 + j][n];
        }
        size_t base = ((size_t)b * NN + n0 + n) * DKK + d0;
        *(bf16x4*)&qws[base] = qv;
        *(bf16x4*)&kws[base] = kv;
    }
}

// ---------------------------------------------------------------------------
// Kernel 2: flash attention — R5's 32x32-MFMA structure VERBATIM (the best
// measured: 54.2us; R7 zero-LDS serial = 60, R8 reg-pipe = 57, R9 c-split
// barrier = 68 all lost). n-split waves, zero-barrier main loop, wave-
// private LDS P double-buffer (the 1-deep pipeline), 64m x 128c blocks,
// grid 512 @ 2 blocks/CU. Micro-fix this round: lacc accumulated via
// per-group partials (breaks a 16-deep serial fp-add chain in the exp
// phase). acc = 8 x f32x16 = 128 AGPR; VGPR stays <=128.
// ---------------------------------------------------------------------------
#define PSTD 18                    // P row pitch (dwords) = 72B
#define PWB  (64 * PSTD * 4)       // one P buffer bytes = 4608
#define MST 68                     // O-reduce row stride (dwords)

__global__ __launch_bounds__(256, 2) void attn_kernel(
    const __bf16* __restrict__ qb, const __bf16* __restrict__ kb,
    const __bf16* __restrict__ vt, const float* __restrict__ x,
    float* __restrict__ out)
{
    // [0, 36864)       pbuf: 4 waves x 2 bufs x 64 rows x 72B
    // [0, 34816)       Ored overlay (epilogue): 4 waves x 32 x MST fp32
    // [36864, 37888)   Ls[4][64]
    // [37888, 38144)   Linv[64]
    __shared__ __align__(16) unsigned char smem[38144];
    const int tid = threadIdx.x;
    const int w   = tid >> 6;
    const int l   = tid & 63;
    const int m31 = l & 31;           // MFMA col lane (m / A-row)
    const int hi  = l >> 5;           // k-half lane
    const int mx  = m31 & 3;          // LDS slot-XOR key
    unsigned char* pwb = smem + w * 2 * PWB;   // wave-private P buffers
    float* Ls   = (float*)(smem + 36864);
    float* Linv = (float*)(smem + 37888);

    // XCD swizzle: batch pinned to an XCD pair -> K/V/Q stay L2-resident
    const int beta = blockIdx.x;
    const int b    = (beta >> 1) & 3;
    const int ch   = (beta >> 3) & 1;                        // c-half
    const int mt64 = ((beta >> 4) << 1) | (beta & 1);        // 0..63
    const int m0   = mt64 * 64;

    const __bf16* qbb = qb + (size_t)b * NN * DKK;
    const __bf16* kbb = kb + (size_t)b * NN * DKK;
    const __bf16* vtb = vt + (size_t)b * CC * NN;

    // Q B-frags: qa[mt][kb2]: Q[m0+mt*32+m31][kb2*16 + hi*8 + j]
    bf16x8 qa[2][2];
#pragma unroll
    for (int mt = 0; mt < 2; mt++)
#pragma unroll
        for (int kk = 0; kk < 2; kk++)
            qa[mt][kk] = *(const bf16x8*)(qbb + (size_t)(m0 + mt * 32 + m31) * DKK + kk * 16 + hi * 8);

    // K A-frag strip: K[w*32 + m31 + 128*ic][kb*16 + hi*8 + j]
    const __bf16* kstrip = kbb + (size_t)(w * 32 + m31) * DKK + hi * 8;
    // V A-frag strip: tile (chunk=ic*4+w, ct, kb), lane (c=m31, n=hi*8+j)
    const __bf16* vstrip = vtb + (size_t)w * 8192 + (size_t)ch * 4096
                               + m31 * 16 + hi * 8;

    const f32x16 zf16 = {0.f,0.f,0.f,0.f,0.f,0.f,0.f,0.f,
                         0.f,0.f,0.f,0.f,0.f,0.f,0.f,0.f};
    f32x16 acc[4][2];                 // [ct][mt] = 128 AGPR
#pragma unroll
    for (int ct = 0; ct < 4; ct++)
#pragma unroll
        for (int mt = 0; mt < 2; mt++) acc[ct][mt] = zf16;
    float lacc[2] = {0.f, 0.f};

    // KQ step: e = K·Q^T (32n x 32m per mt), exp2, pack to bf16x4 groups,
    // store to P buffer at byte offset bufoff. n(reg) = (reg&3)+8(reg>>2)+4hi.
    // Group g (regs 4g..4g+3) -> slot (g^mx), byte hi*8. lacc via per-group
    // partials (chain depth 6, was 16).
    auto kq_step = [&](int bufoff, bf16x8 kA0, bf16x8 kA1) {
#pragma unroll
        for (int mt = 0; mt < 2; mt++) {
            f32x16 e = __builtin_amdgcn_mfma_f32_32x32x16_bf16(kA0, qa[mt][0], zf16, 0, 0, 0);
            e = __builtin_amdgcn_mfma_f32_32x32x16_bf16(kA1, qa[mt][1], e, 0, 0, 0);
            float sg[4];
#pragma unroll
            for (int g = 0; g < 4; g++) {
                bf16x4 pb;
                float s = 0.f;
#pragma unroll
                for (int t = 0; t < 4; t++) {
                    float v = __builtin_amdgcn_exp2f(e[4 * g + t]);
                    s += v; pb[t] = (__bf16)v;
                }
                sg[g] = s;
                *(bf16x4*)(pwb + bufoff + (mt * 32 + m31) * 72 + ((g ^ mx) * 16 + hi * 8)) = pb;
            }
            lacc[mt] += (sg[0] + sg[1]) + (sg[2] + sg[3]);
        }
    };

    // P B-frag read: pf[mt][kk] needs P[n = kk*16+hi*8+j][m=mt*32+m31]
    // = slot (kk*2+hi)^mx, two b64 at +0,+8.
    union PU { bf16x8 v; bf16x4 h[2]; };
    auto pf_read = [&](int bufoff, bf16x8 (&pf)[2][2]) {
#pragma unroll
        for (int mt = 0; mt < 2; mt++)
#pragma unroll
            for (int kk = 0; kk < 2; kk++) {
                int sb = (((kk * 2 + hi) ^ mx) * 16);
                PU u;
                u.h[0] = *(const bf16x4*)(pwb + bufoff + (mt * 32 + m31) * 72 + sb);
                u.h[1] = *(const bf16x4*)(pwb + bufoff + (mt * 32 + m31) * 72 + sb + 8);
                pf[mt][kk] = u.v;
            }
    };

    // ---- prologue: P(0) -> buf 0; prefetch k(1) ----
    {
        bf16x8 kA0 = *(const bf16x8*)kstrip;
        bf16x8 kA1 = *(const bf16x8*)(kstrip + 16);
        kq_step(0, kA0, kA1);
    }
    bf16x8 kA0 = *(const bf16x8*)(kstrip + (size_t)128 * DKK);
    bf16x8 kA1 = *(const bf16x8*)(kstrip + (size_t)128 * DKK + 16);

    // ---- main loop: zero barriers, purely intra-wave ----
#pragma unroll 2
    for (int ic = 0; ic < 31; ic++) {
        const int cur = ic & 1;
        const __bf16* vch = vstrip + (size_t)ic * 32768;

        // V kb0 group in flight early (KQ/exp covers its latency)
        bf16x8 vA[4], vB[4];
#pragma unroll
        for (int ct = 0; ct < 4; ct++)
            vA[ct] = *(const bf16x8*)(vch + ct * 1024);

        // P(ic) fragments from buf[cur] (written last iter)
        bf16x8 pf[2][2];
        pf_read(cur * PWB, pf);

        // KQ(ic+1) + exp into buf[cur^1]
        kq_step((cur ^ 1) * PWB, kA0, kA1);

        // V kb1 group
#pragma unroll
        for (int ct = 0; ct < 4; ct++)
            vB[ct] = *(const bf16x8*)(vch + ct * 1024 + 512);

        // prefetch k(ic+2) (OOB at tail lands in adjacent ws region — unused)
        kA0 = *(const bf16x8*)(kstrip + (size_t)(ic + 2) * 128 * DKK);
        kA1 = *(const bf16x8*)(kstrip + (size_t)(ic + 2) * 128 * DKK + 16);

        // PV(ic): 8 tiles x 2 chained k-halves
        __builtin_amdgcn_s_setprio(1);
#pragma unroll
        for (int ct = 0; ct < 4; ct++)
#pragma unroll
            for (int mt = 0; mt < 2; mt++) {
                acc[ct][mt] = __builtin_amdgcn_mfma_f32_32x32x16_bf16(vA[ct], pf[mt][0], acc[ct][mt], 0, 0, 0);
                acc[ct][mt] = __builtin_amdgcn_mfma_f32_32x32x16_bf16(vB[ct], pf[mt][1], acc[ct][mt], 0, 0, 0);
            }
        __builtin_amdgcn_s_setprio(0);
    }

    // ---- peel: PV(31) ----
    {
        const __bf16* vch = vstrip + (size_t)31 * 32768;
        bf16x8 pf[2][2];
        pf_read(PWB, pf);                 // 31&1 = 1
        bf16x8 vA[4], vB[4];
#pragma unroll
        for (int ct = 0; ct < 4; ct++) vA[ct] = *(const bf16x8*)(vch + ct * 1024);
#pragma unroll
        for (int ct = 0; ct < 4; ct++) vB[ct] = *(const bf16x8*)(vch + ct * 1024 + 512);
        __builtin_amdgcn_s_setprio(1);
#pragma unroll
        for (int ct = 0; ct < 4; ct++)
#pragma unroll
            for (int mt = 0; mt < 2; mt++) {
                acc[ct][mt] = __builtin_amdgcn_mfma_f32_32x32x16_bf16(vA[ct], pf[mt][0], acc[ct][mt], 0, 0, 0);
                acc[ct][mt] = __builtin_amdgcn_mfma_f32_32x32x16_bf16(vB[ct], pf[mt][1], acc[ct][mt], 0, 0, 0);
            }
        __builtin_amdgcn_s_setprio(0);
    }

    // ---- l: intra-wave reduce (lanes l and l+32 share m), publish ----
#pragma unroll
    for (int mt = 0; mt < 2; mt++) lacc[mt] += __shfl_xor(lacc[mt], 32, 64);
    if (hi == 0) {
#pragma unroll
        for (int mt = 0; mt < 2; mt++) Ls[w * 64 + mt * 32 + m31] = lacc[mt];
    }
    __syncthreads();
    if (tid < 64)
        Linv[tid] = 1.0f / (Ls[tid] + Ls[64 + tid] + Ls[128 + tid] + Ls[192 + tid]);

    // ---- epilogue: cross-wave O reduce, one 32-c quarter per ct ----
    // acc[ct][mt][reg]: c = ch*128 + ct*32 + crow, crow=(reg&3)+8(reg>>2)+4hi;
    // m = mt*32 + m31.
    float* Ored = (float*)smem + w * (32 * MST);
#pragma unroll
    for (int q = 0; q < 4; q++) {
        if (q > 0) __syncthreads();       // prior quarter's reads done
#pragma unroll
        for (int mt = 0; mt < 2; mt++)
#pragma unroll
            for (int reg = 0; reg < 16; reg++) {
                int crow = (reg & 3) + 8 * (reg >> 2) + 4 * hi;
                Ored[crow * MST + mt * 32 + m31] = acc[q][mt][reg];
            }
        __syncthreads();
        // sum 4 wave-partials, normalize, residual, store
        const int cl  = tid >> 3;         // 0..31 (c within quarter)
        const int mi0 = (tid & 7) * 8;    // m offset
        const float* Ob = (const float*)smem + cl * MST;
#pragma unroll
        for (int j = 0; j < 2; j++) {
            int mi = mi0 + 4 * j;
            f32x4 s = *(const f32x4*)&Ob[mi];
            s = s + *(const f32x4*)&Ob[1 * (32 * MST) + mi];
            s = s + *(const f32x4*)&Ob[2 * (32 * MST) + mi];
            s = s + *(const f32x4*)&Ob[3 * (32 * MST) + mi];
            f32x4 li = *(const f32x4*)&Linv[mi];
            int c = ch * 128 + q * 32 + cl;
            size_t gi = ((size_t)(b * CC + c)) * NN + m0 + mi;
            f32x4 xr = *(const f32x4*)&x[gi];
            *(f32x4*)&out[gi] = s * li + xr;
        }
    }
}

extern "C" void kernel_launch(void* const* d_in, const int* in_sizes, int n_in,
                              void* d_out, int out_size, void* d_ws, size_t ws_size,
                              hipStream_t stream) {
    const float* x  = (const float*)d_in[0];
    const float* Wq = (const float*)d_in[1];
    const float* bq = (const float*)d_in[2];
    const float* Wk = (const float*)d_in[3];
    const float* bk = (const float*)d_in[4];
    const float* Wv = (const float*)d_in[5];
    const float* bv = (const float*)d_in[6];
    float* out = (float*)d_out;

    __bf16* qws = (__bf16*)d_ws;                       // B*N*32
    __bf16* kws = qws + (size_t)BB * NN * DKK;         // B*N*32
    __bf16* vws = kws + (size_t)BB * NN * DKK;         // B*C*N (tiled)
    __bf16* Wb  = vws + (size_t)BB * CC * NN;          // 320*256
    __bf16* xT  = Wb  + (size_t)320 * CC;              // B*N*C

    prep_kernel<<<dim3(64, 4, BB), 256, 0, stream>>>(x, xT, Wq, Wk, Wv, Wb);
    qkv_kernel <<<dim3(128, BB), 256, 0, stream>>>(xT, Wb, bq, bk, bv, qws, kws, vws);
    attn_kernel<<<dim3(512), 256, 0, stream>>>(qws, kws, vws, x, out);
}